// Round 4
// baseline (874.249 us; speedup 1.0000x reference)
//
#include <hip/hip_runtime.h>
#include <hip/hip_bf16.h>

#define NUM_E 64
#define KTOP 8
#define CAP 512
#define TT 2048
#define DD 2048
#define HH 1024

#define BK 32
#define LDSK 36  // 72B rows: all b64 access classes at the 4-lane/bank minimum

typedef __attribute__((ext_vector_type(4))) float f4v;
typedef __attribute__((ext_vector_type(8))) short bf16x8;
typedef __attribute__((ext_vector_type(4))) short bf16x4;

static __device__ __forceinline__ short f2bf(float f) {
    __bf16 b = (__bf16)f;
    return __builtin_bit_cast(short, b);
}

// Raw barrier WITHOUT vmcnt drain: LDS writes must be committed (lgkmcnt(0)),
// but global loads in flight stay in flight across the barrier (T4).
static __device__ __forceinline__ void pipe_barrier() {
    asm volatile("s_waitcnt lgkmcnt(0)" ::: "memory");
    __builtin_amdgcn_s_barrier();
}

// ---------------- init: zero out[] and counts[] ----------------
__global__ __launch_bounds__(256) void k_init(float* __restrict__ out, int* __restrict__ counts) {
    int idx = blockIdx.x * 256 + threadIdx.x;
    f4v z = {0.f, 0.f, 0.f, 0.f};
    f4v* o4 = (f4v*)out;
    for (int i = idx; i < (TT * DD) / 4; i += 1024 * 256) o4[i] = z;
    if (idx < NUM_E) counts[idx] = 0;
}

// ---------------- router: logits = x @ gate_w (f32) ----------------
#define RTOK 8
__global__ __launch_bounds__(256) void k_router(const float* __restrict__ x,
                                                const float* __restrict__ gw,
                                                float* __restrict__ logits) {
    __shared__ float xs[RTOK][512];
    const int tid = threadIdx.x;
    const int lane = tid & 63, wid = tid >> 6;
    const int t0 = blockIdx.x * RTOK;
    float a0 = 0.f, a1 = 0.f;
    for (int c = 0; c < DD / 512; ++c) {
        __syncthreads();
#pragma unroll
        for (int u = tid * 4; u < RTOK * 512; u += 1024) {
            int r = u >> 9, col = u & 511;
            *(f4v*)&xs[r][col] = *(const f4v*)&x[(size_t)(t0 + r) * DD + c * 512 + col];
        }
        __syncthreads();
        const float* gcol = gw + (size_t)c * 512 * NUM_E + lane;
#pragma unroll 8
        for (int d = 0; d < 512; ++d) {
            float g = gcol[(size_t)d * NUM_E];
            a0 = fmaf(xs[wid * 2 + 0][d], g, a0);
            a1 = fmaf(xs[wid * 2 + 1][d], g, a1);
        }
    }
    logits[(size_t)(t0 + wid * 2 + 0) * NUM_E + lane] = a0;
    logits[(size_t)(t0 + wid * 2 + 1) * NUM_E + lane] = a1;
}

// ---------------- topk + dispatch ----------------
__global__ __launch_bounds__(256) void k_topk(const float* __restrict__ logits,
                                              int* __restrict__ counts,
                                              int* __restrict__ slot_token,
                                              float* __restrict__ slot_wt) {
    int lane = threadIdx.x & 63, wid = threadIdx.x >> 6;
    int t = blockIdx.x * 4 + wid;
    float l = logits[(size_t)t * NUM_E + lane];
    float m = l;
#pragma unroll
    for (int off = 32; off; off >>= 1) m = fmaxf(m, __shfl_xor(m, off));
    float ex = __expf(l - m);
    float s = ex;
#pragma unroll
    for (int off = 32; off; off >>= 1) s += __shfl_xor(s, off);
    float p = ex / s;
#pragma unroll
    for (int k = 0; k < KTOP; ++k) {
        float v = p;
        int i = lane;
#pragma unroll
        for (int off = 32; off; off >>= 1) {
            float v2 = __shfl_xor(v, off);
            int i2 = __shfl_xor(i, off);
            if (v2 > v || (v2 == v && i2 < i)) { v = v2; i = i2; }
        }
        if (lane == i) {
            int pos = atomicAdd(&counts[i], 1);
            if (pos < CAP) {
                int slot = i * CAP + pos;
                slot_token[slot] = t;
                slot_wt[slot] = v;
            }
            p = -1.0f;
        }
    }
}

// ---------------- gate+up fused GEMM + SwiGLU -> h ----------------
// 128x64 block tile, 4 waves; 2-stage reg prefetch + double-buffered LDS,
// single raw barrier per K-step, counted vmcnt (loads live across barriers).
#define GU_LOAD(AR, BR, KO) { \
    _Pragma("unroll") for (int i_ = 0; i_ < 4; ++i_) if (aptr[i_]) AR[i_] = *(const f4v*)(aptr[i_] + (KO)); \
    _Pragma("unroll") for (int j_ = 0; j_ < 4; ++j_) BR[j_] = *(const f4v*)(bptr + ((size_t)(KO) + j_) * HH); }

#define GU_WRITE(AR, BR, ASB, BLB) { \
    _Pragma("unroll") for (int i_ = 0; i_ < 4; ++i_) { \
        bf16x4 pk_ = {f2bf(AR[i_][0]), f2bf(AR[i_][1]), f2bf(AR[i_][2]), f2bf(AR[i_][3])}; \
        *(bf16x4*)&ASB[arow[i_] * LDSK + ak] = pk_; } \
    _Pragma("unroll") for (int i_ = 0; i_ < 4; ++i_) { \
        bf16x4 col_ = {f2bf(BR[0][i_]), f2bf(BR[1][i_]), f2bf(BR[2][i_]), f2bf(BR[3][i_])}; \
        *(bf16x4*)&BLB[(bh + i_) * LDSK + bk] = col_; } }

#define GU_FRAG(AS, BG, BU) { \
    _Pragma("unroll") for (int m_ = 0; m_ < 4; ++m_) { \
        const ushort* pa_ = &AS[(wm * 64 + m_ * 16 + lrow) * LDSK + g4 * 4]; \
        union { bf16x8 v8; bf16x4 v4[2]; } u_; \
        u_.v4[0] = *(const bf16x4*)pa_; u_.v4[1] = *(const bf16x4*)(pa_ + 16); \
        af[m_] = u_.v8; } \
    _Pragma("unroll") for (int n_ = 0; n_ < 2; ++n_) { \
        const int c_ = (wn * 32 + n_ * 16 + lrow) * LDSK + g4 * 4; \
        union { bf16x8 v8; bf16x4 v4[2]; } ug_, uu_; \
        ug_.v4[0] = *(const bf16x4*)&BG[c_]; ug_.v4[1] = *(const bf16x4*)&BG[c_ + 16]; \
        uu_.v4[0] = *(const bf16x4*)&BU[c_]; uu_.v4[1] = *(const bf16x4*)&BU[c_ + 16]; \
        bgr[n_] = ug_.v8; bur[n_] = uu_.v8; } }

#define GU_MFMA() { \
    __builtin_amdgcn_s_setprio(1); \
    _Pragma("unroll") for (int n_ = 0; n_ < 2; ++n_) \
    _Pragma("unroll") for (int m_ = 0; m_ < 4; ++m_) { \
        accg[m_][n_] = __builtin_amdgcn_mfma_f32_16x16x32_bf16(af[m_], bgr[n_], accg[m_][n_], 0, 0, 0); \
        accu[m_][n_] = __builtin_amdgcn_mfma_f32_16x16x32_bf16(af[m_], bur[n_], accu[m_][n_], 0, 0, 0); } \
    __builtin_amdgcn_s_setprio(0); }

__global__ __launch_bounds__(256, 2) void k_gateup(
    const float* __restrict__ x, const float* __restrict__ wg, const float* __restrict__ wu,
    const int* __restrict__ counts, const int* __restrict__ slot_token,
    const float* __restrict__ slot_wt, ushort* __restrict__ hbuf) {
    const int e = blockIdx.z;
    int count = counts[e];
    if (count > CAP) count = CAP;
    const int mrow0 = blockIdx.y * 128;
    if (mrow0 >= count) return;
    const int ncol0 = blockIdx.x * 64;
    const int tid = threadIdx.x;
    const int lane = tid & 63, wid = tid >> 6;
    const int wm = wid >> 1, wn = wid & 1;
    const int lrow = lane & 15, g4 = lane >> 4;

    __shared__ ushort As0[128 * LDSK], As1[128 * LDSK];
    __shared__ ushort Bg0[64 * LDSK], Bg1[64 * LDSK];
    __shared__ ushort Bu0[64 * LDSK], Bu1[64 * LDSK];

    const int ak = (tid & 7) * 4;
    const float* aptr[4];
    int arow[4];
#pragma unroll
    for (int i = 0; i < 4; ++i) {
        int r = i * 32 + (tid >> 3);
        arow[i] = r;
        int rg = mrow0 + r;
        if (rg < count) {
            int tok = slot_token[e * CAP + rg];
            aptr[i] = x + (size_t)tok * DD + ak;
        } else {
            aptr[i] = nullptr;
        }
    }

    const int bu_idx = tid & 127;
    const int bh = (bu_idx & 15) * 4;
    const int bk = (bu_idx >> 4) * 4;
    const float* bptr = ((tid < 128) ? wg : wu) + ((size_t)e * DD + bk) * HH + ncol0 + bh;
    ushort* bl0 = (tid < 128) ? Bg0 : Bu0;
    ushort* bl1 = (tid < 128) ? Bg1 : Bu1;

    const f4v fz = {0.f, 0.f, 0.f, 0.f};
    f4v a0r[4], b0r[4], a1r[4], b1r[4];
#pragma unroll
    for (int i = 0; i < 4; ++i) { a0r[i] = fz; b0r[i] = fz; a1r[i] = fz; b1r[i] = fz; }

    f4v accg[4][2], accu[4][2];
#pragma unroll
    for (int m = 0; m < 4; ++m)
#pragma unroll
        for (int n = 0; n < 2; ++n) { accg[m][n] = fz; accu[m][n] = fz; }

    bf16x8 af[4], bgr[2], bur[2];

    // prologue: tiles 0,1 in flight; write tile 0 (counted vmcnt leaves tile 1 in flight)
    GU_LOAD(a0r, b0r, 0);
    GU_LOAD(a1r, b1r, BK);
    GU_WRITE(a0r, b0r, As0, bl0);
    pipe_barrier();

    const int NK = DD / BK;  // 64, even
    for (int kt = 0; kt < NK; kt += 2) {
        // step A: consume buf0 (tile kt)
        if (kt + 2 < NK) GU_LOAD(a0r, b0r, (kt + 2) * BK);
        GU_FRAG(As0, Bg0, Bu0);
        GU_WRITE(a1r, b1r, As1, bl1);  // tile kt+1
        GU_MFMA();
        pipe_barrier();
        // step B: consume buf1 (tile kt+1)
        if (kt + 3 < NK) GU_LOAD(a1r, b1r, (kt + 3) * BK);
        GU_FRAG(As1, Bg1, Bu1);
        if (kt + 2 < NK) GU_WRITE(a0r, b0r, As0, bl0);  // tile kt+2
        GU_MFMA();
        pipe_barrier();
    }

    // epilogue: h = silu(g)*u * gate-weight, bf16
#pragma unroll
    for (int m = 0; m < 4; ++m) {
#pragma unroll
        for (int r = 0; r < 4; ++r) {
            int row = mrow0 + wm * 64 + m * 16 + g4 * 4 + r;
            if (row < count) {
                float wgt = slot_wt[e * CAP + row];
                size_t base = (size_t)(e * CAP + row) * HH + ncol0 + wn * 32;
#pragma unroll
                for (int n = 0; n < 2; ++n) {
                    float g = accg[m][n][r], uv = accu[m][n][r];
                    float hv = (g / (1.f + __expf(-g))) * uv * wgt;
                    hbuf[base + n * 16 + lrow] = (ushort)f2bf(hv);
                }
            }
        }
    }
}

// ---------------- down GEMM + scatter-add into out ----------------
#define DN_LOAD(AR, BR, KO) { \
    _Pragma("unroll") for (int i_ = 0; i_ < 2; ++i_) if (aval[i_]) AR[i_] = *(const bf16x8*)(haptr[i_] + (KO)); \
    _Pragma("unroll") for (int j_ = 0; j_ < 4; ++j_) BR[j_] = *(const f4v*)(bptr + ((size_t)(KO) + j_) * DD); }

#define DN_WRITE(AR, BR, ASB, BSB) { \
    _Pragma("unroll") for (int i_ = 0; i_ < 2; ++i_) { \
        union { bf16x8 v8; bf16x4 v4[2]; } u_; u_.v8 = AR[i_]; \
        *(bf16x4*)&ASB[arow[i_] * LDSK + k8] = u_.v4[0]; \
        *(bf16x4*)&ASB[arow[i_] * LDSK + k8 + 4] = u_.v4[1]; } \
    _Pragma("unroll") for (int i_ = 0; i_ < 4; ++i_) { \
        bf16x4 col_ = {f2bf(BR[0][i_]), f2bf(BR[1][i_]), f2bf(BR[2][i_]), f2bf(BR[3][i_])}; \
        *(bf16x4*)&BSB[(d0 + i_) * LDSK + k0] = col_; } }

#define DN_FRAG(AS, BS) { \
    _Pragma("unroll") for (int m_ = 0; m_ < 4; ++m_) { \
        const ushort* pa_ = &AS[(wm * 64 + m_ * 16 + lrow) * LDSK + g4 * 4]; \
        union { bf16x8 v8; bf16x4 v4[2]; } u_; \
        u_.v4[0] = *(const bf16x4*)pa_; u_.v4[1] = *(const bf16x4*)(pa_ + 16); \
        af[m_] = u_.v8; } \
    _Pragma("unroll") for (int n_ = 0; n_ < 4; ++n_) { \
        const int c_ = (wn * 64 + n_ * 16 + lrow) * LDSK + g4 * 4; \
        union { bf16x8 v8; bf16x4 v4[2]; } ub_; \
        ub_.v4[0] = *(const bf16x4*)&BS[c_]; ub_.v4[1] = *(const bf16x4*)&BS[c_ + 16]; \
        bfr[n_] = ub_.v8; } }

#define DN_MFMA() { \
    __builtin_amdgcn_s_setprio(1); \
    _Pragma("unroll") for (int n_ = 0; n_ < 4; ++n_) \
    _Pragma("unroll") for (int m_ = 0; m_ < 4; ++m_) \
        acc[m_][n_] = __builtin_amdgcn_mfma_f32_16x16x32_bf16(af[m_], bfr[n_], acc[m_][n_], 0, 0, 0); \
    __builtin_amdgcn_s_setprio(0); }

__global__ __launch_bounds__(256, 2) void k_down(
    const ushort* __restrict__ hbuf, const float* __restrict__ wd,
    const int* __restrict__ counts, const int* __restrict__ slot_token,
    float* __restrict__ out) {
    const int e = blockIdx.z;
    int count = counts[e];
    if (count > CAP) count = CAP;
    const int mrow0 = blockIdx.y * 128;
    if (mrow0 >= count) return;
    const int ncol0 = blockIdx.x * 128;
    const int tid = threadIdx.x;
    const int lane = tid & 63, wid = tid >> 6;
    const int wm = wid >> 1, wn = wid & 1;
    const int lrow = lane & 15, g4 = lane >> 4;

    __shared__ ushort As0[128 * LDSK], As1[128 * LDSK];
    __shared__ ushort Bs0[128 * LDSK], Bs1[128 * LDSK];

    const int k8 = (tid & 3) * 8;
    bool aval[2];
    const ushort* haptr[2];
    int arow[2];
#pragma unroll
    for (int i = 0; i < 2; ++i) {
        int r = i * 64 + (tid >> 2);
        arow[i] = r;
        int rg = mrow0 + r;
        aval[i] = rg < count;
        haptr[i] = hbuf + (size_t)(e * CAP + (rg < CAP ? rg : 0)) * HH + k8;
    }
    const int dgrp = (tid & 15) | ((tid >> 7) << 4);   // 0..31
    const int kgrp = (tid >> 4) & 7;                   // 0..7
    const int d0 = dgrp * 4;
    const int k0 = kgrp * 4;
    const float* bptr = wd + ((size_t)e * HH + k0) * DD + ncol0 + d0;

    const f4v fz = {0.f, 0.f, 0.f, 0.f};
    const bf16x8 bz = {0, 0, 0, 0, 0, 0, 0, 0};
    bf16x8 a0r[2], a1r[2];
    f4v b0r[4], b1r[4];
    a0r[0] = bz; a0r[1] = bz; a1r[0] = bz; a1r[1] = bz;
#pragma unroll
    for (int j = 0; j < 4; ++j) { b0r[j] = fz; b1r[j] = fz; }

    f4v acc[4][4];
#pragma unroll
    for (int m = 0; m < 4; ++m)
#pragma unroll
        for (int n = 0; n < 4; ++n) acc[m][n] = fz;

    bf16x8 af[4], bfr[4];

    DN_LOAD(a0r, b0r, 0);
    DN_LOAD(a1r, b1r, BK);
    DN_WRITE(a0r, b0r, As0, Bs0);
    pipe_barrier();

    const int NK = HH / BK;  // 32, even
    for (int kt = 0; kt < NK; kt += 2) {
        if (kt + 2 < NK) DN_LOAD(a0r, b0r, (kt + 2) * BK);
        DN_FRAG(As0, Bs0);
        DN_WRITE(a1r, b1r, As1, Bs1);
        DN_MFMA();
        pipe_barrier();
        if (kt + 3 < NK) DN_LOAD(a1r, b1r, (kt + 3) * BK);
        DN_FRAG(As1, Bs1);
        if (kt + 2 < NK) DN_WRITE(a0r, b0r, As0, Bs0);
        DN_MFMA();
        pipe_barrier();
    }

#pragma unroll
    for (int m = 0; m < 4; ++m) {
#pragma unroll
        for (int r = 0; r < 4; ++r) {
            int row = mrow0 + wm * 64 + m * 16 + g4 * 4 + r;
            if (row < count) {
                int tok = slot_token[e * CAP + row];
                float* obase = out + (size_t)tok * DD + ncol0 + wn * 64;
#pragma unroll
                for (int n = 0; n < 4; ++n) atomicAdd(obase + n * 16 + lrow, acc[m][n][r]);
            }
        }
    }
}

extern "C" void kernel_launch(void* const* d_in, const int* in_sizes, int n_in,
                              void* d_out, int out_size, void* d_ws, size_t ws_size,
                              hipStream_t stream) {
    const float* x = (const float*)d_in[0];       // [1,2048,2048]
    const float* gw = (const float*)d_in[1];      // [2048,64]
    const float* wg = (const float*)d_in[2];      // [64,2048,1024]
    const float* wu = (const float*)d_in[3];      // [64,2048,1024]
    const float* wd = (const float*)d_in[4];      // [64,1024,2048]
    float* out = (float*)d_out;                   // [T*D] then logits [T*E]
    float* logits = out + (size_t)TT * DD;

    char* ws = (char*)d_ws;
    int* counts = (int*)ws;                                      // 256 B
    int* slot_token = (int*)(ws + 1024);                         // 128 KB
    float* slot_wt = (float*)(ws + 1024 + NUM_E * CAP * 4);      // 128 KB
    ushort* hbuf = (ushort*)(ws + 1024 + 2 * NUM_E * CAP * 4);   // 64 MB bf16 [E*CAP][H]

    k_init<<<1024, 256, 0, stream>>>(out, counts);
    k_router<<<TT / RTOK, 256, 0, stream>>>(x, gw, logits);
    k_topk<<<TT / 4, 256, 0, stream>>>(logits, counts, slot_token, slot_wt);
    k_gateup<<<dim3(HH / 64, CAP / 128, NUM_E), 256, 0, stream>>>(x, wg, wu, counts, slot_token, slot_wt, hbuf);
    k_down<<<dim3(DD / 128, CAP / 128, NUM_E), 256, 0, stream>>>(hbuf, wd, counts, slot_token, out);
}